// Round 7
// baseline (285.141 us; speedup 1.0000x reference)
//
#include <hip/hip_runtime.h>
#include <hip/hip_cooperative_groups.h>
#include <cstdint>

namespace cg = cooperative_groups;

// B=2, Q=512, K=512, T=256 (fp32 in/out).
// R14: single cooperative kernel, 256 blocks x 512 thr (1 block/CU), two
// grid.sync()s. Phase 1 = projections (R13 32x64 pipelined GEMM as 2x256-thr
// virtual units/block) + WalF + vsum/out zero. Phase 2 = kernelC EXACTLY R11
// (110us proven: 8 waves x 64q x 32u, shfl stats, lg/acc pinned, rcp).
// Phase 3 = out GEMM, split-K x4, atomicAdd.
//   p = x*exp(x); M = max_q x, S = sum_q |p|; acc += p * g,
//   g = vproj*e^-M / (S*e^-M + 1).

typedef short bf16x8 __attribute__((ext_vector_type(8)));   // 8 bf16 = 4 VGPR
typedef float f32x4  __attribute__((ext_vector_type(4)));   // MFMA C/D frag

__device__ inline float bf2f(short s) {
  return __uint_as_float(((unsigned)(unsigned short)s) << 16);
}
// f32 pair -> packed bf16 (round-half-up), low short = lo
__device__ inline unsigned packrn(float lo, float hi) {
  return __builtin_amdgcn_perm(__float_as_uint(hi) + 0x8000u,
                               __float_as_uint(lo) + 0x8000u, 0x07060302u);
}
// monotone (unsigned) encoding of f32 for atomic max; 0 == "-infinity" sentinel
__device__ inline unsigned encM(float f) {
  unsigned k = (unsigned)__float_as_int(f);
  return (k & 0x80000000u) ? ~k : (k | 0x80000000u);
}
__device__ inline float decM(unsigned k) {
  int i = (k & 0x80000000u) ? (int)(k ^ 0x80000000u) : (int)~k;
  return __int_as_float(i);
}

union Frag { bf16x8 v; unsigned u[4]; };

// 32x64-tile fp32 GEMM over K range [K0,K1), 256-thread virtual unit,
// prefetch-pipelined. As: 16x36 f32, Ws: 16x68 f32 (caller-aliased LDS).
// c[2][4]: rows m0+ (t>>4)*2 +{0,1}, cols u0+(t&15)*4+{0..3}.
// NOTE: __syncthreads() syncs the whole 512-thr block; both virtual units
// run identical trip counts so barriers stay uniform.
__device__ __forceinline__ void gemm32_body(
    const float* __restrict__ X, const float* __restrict__ W,
    float* __restrict__ As, float* __restrict__ Ws,
    int m0, int u0, int K0, int K1, int t, float c[2][4])
{
  const int lmi = t >> 2, lc4 = (t & 3) * 4;
  const int tx4 = (t & 15) * 4;
  const int ty2 = (t >> 4) * 2;
  const bool hasA = t < 128;
  float4 xa, wb;
  if (hasA) xa = *(const float4*)&X[(size_t)(m0 + lmi) * 256 + K0 + lc4];
  wb = *(const float4*)&W[(size_t)(u0 + lmi) * 256 + K0 + lc4];
#pragma unroll 1
  for (int t0 = K0; t0 < K1; t0 += 16) {
    __syncthreads();
    if (hasA) {
      As[(lc4 + 0) * 36 + lmi] = xa.x; As[(lc4 + 1) * 36 + lmi] = xa.y;
      As[(lc4 + 2) * 36 + lmi] = xa.z; As[(lc4 + 3) * 36 + lmi] = xa.w;
    }
    Ws[(lc4 + 0) * 68 + lmi] = wb.x; Ws[(lc4 + 1) * 68 + lmi] = wb.y;
    Ws[(lc4 + 2) * 68 + lmi] = wb.z; Ws[(lc4 + 3) * 68 + lmi] = wb.w;
    __syncthreads();
    if (t0 + 16 < K1) {
      if (hasA) xa = *(const float4*)&X[(size_t)(m0 + lmi) * 256 + t0 + 16 + lc4];
      wb = *(const float4*)&W[(size_t)(u0 + lmi) * 256 + t0 + 16 + lc4];
    }
#pragma unroll
    for (int tt = 0; tt < 16; ++tt) {
      const float2 a = *(const float2*)&As[tt * 36 + ty2];
      const float4 wv = *(const float4*)&Ws[tt * 68 + tx4];
      c[0][0] += a.x * wv.x; c[0][1] += a.x * wv.y;
      c[0][2] += a.x * wv.z; c[0][3] += a.x * wv.w;
      c[1][0] += a.y * wv.x; c[1][1] += a.y * wv.y;
      c[1][2] += a.y * wv.z; c[1][3] += a.y * wv.w;
    }
  }
}

__global__ __launch_bounds__(512, 2) void fused(
    const float* __restrict__ query, const float* __restrict__ key,
    const float* __restrict__ value, const float* __restrict__ Wk,
    const float* __restrict__ Wq, const float* __restrict__ Wva,
    const float* __restrict__ Wal, const float* __restrict__ Wvo,
    float* __restrict__ kproj, float* __restrict__ vproj,
    float* __restrict__ vsum, short* __restrict__ qpF,
    short* __restrict__ WalF, float* __restrict__ out)
{
  // one buffer, re-aliased per phase (phases separated by grid.sync)
  __shared__ __align__(16) unsigned char smem[37888];
  cg::grid_group grid = cg::this_grid();
  const int bid = blockIdx.x;
  const int tid = threadIdx.x;
  const int half = tid >> 8, t = tid & 255;
  const int vb = bid * 2 + half;   // virtual 256-thr unit id, [0,512)

  // ---------------- PHASE 1: projections + aux ----------------
  // vb 0..127 kproj, 128..255 vproj, 256..383 qpF, 384..447 WalF+vsum-zero,
  // 448..511 out-zero. All category boundaries even -> block pairs uniform.
  {
    float* As = (float*)(smem + half * 6656);
    float* Ws = (float*)(smem + half * 6656 + 2304);
    if (vb < 384) {
      const int z = vb >> 7, r = vb & 127;
      const int m0 = (r >> 2) * 32, u0 = (r & 3) * 64;
      const float* X = (z == 0) ? key : (z == 1) ? value : query;
      const float* Wm = (z == 0) ? Wk : (z == 1) ? Wva : Wq;
      float c[2][4] = {};
      gemm32_body(X, Wm, As, Ws, m0, u0, 0, 256, t, c);
      const int tx4 = (t & 15) * 4, ty2 = (t >> 4) * 2;
      if (z == 2) {
        const int tbase = u0 + tx4;               // t coordinate
        const int ks = tbase >> 5, l4f = (tbase & 31) >> 3, j0 = tbase & 7;
#pragma unroll
        for (int i = 0; i < 2; ++i) {
          const int m = m0 + ty2 + i;             // global row = b*512 + q
          const int bb = m >> 9, q = m & 511;
          const int g = q >> 4, l15q = q & 15;
          const size_t idx =
              ((size_t)(((bb * 32 + g) * 8 + ks) * 64) + l4f * 16 + l15q) * 8 + j0;
          uint2 s; s.x = packrn(c[i][0], c[i][1]); s.y = packrn(c[i][2], c[i][3]);
          *(uint2*)&qpF[idx] = s;
        }
      } else {
        float* C = (z == 0) ? kproj : vproj;
#pragma unroll
        for (int i = 0; i < 2; ++i)
          *(float4*)&C[(size_t)(m0 + ty2 + i) * 256 + u0 + tx4] =
              make_float4(c[i][0], c[i][1], c[i][2], c[i][3]);
      }
    } else if (vb < 448) {
      const int p = vb - 384;                     // 0..63
      // WalF: frag-major bf16 copy of Wal
#pragma unroll
      for (int e = 0; e < 4; ++e) {
        const int d = p * 1024 + t * 4 + e;
        const int j = d & 7, uu = (d >> 3) & 31, c8g = d >> 8;
        const int ucx = c8g >> 5, cc = c8g & 31;
        const float v = Wal[(ucx * 32 + uu) * 256 + cc * 8 + j];
        WalF[d] = (short)packrn(v, v);
      }
      float4* vz = (float4*)(vsum + p * 4096);
#pragma unroll
      for (int e = 0; e < 4; ++e) vz[t * 4 + e] = make_float4(0.f, 0.f, 0.f, 0.f);
    } else {
      const int p = vb - 448;                     // 0..63
      float4* oz = (float4*)(out + p * 4096);
#pragma unroll
      for (int e = 0; e < 4; ++e) oz[t * 4 + e] = make_float4(0.f, 0.f, 0.f, 0.f);
    }
  }
  grid.sync();

  // ---------------- PHASE 2: kernelC (EXACT R11 body) ----------------
  {
    short* W2Fp = (short*)smem;                    // [2][8192] bf16
    float* vpS = (float*)(smem + 32768);           // [32*33]
    unsigned* statM = (unsigned*)(smem + 36992);   // 3 slots x 32
    float* statS = (float*)(smem + 37376);         // 3 slots x 32

    const int kt = bid & 15, uc = (bid >> 4) & 7, b = bid >> 7;
    const int u0 = uc * 32, k0 = kt * 32;
    const int lane = tid & 63, w = tid >> 6;       // w in [0,8)
    const int l15 = lane & 15, l4 = lane >> 4;
    const int uu = tid & 31, c8 = tid >> 5;        // build: c8 and c8+16

    if (tid < 96) { statM[tid] = 0u; statS[tid] = 0.f; }
    {
      const int kk = tid >> 4, uu2 = (tid & 15) * 2;
      const float2 v2 = *(const float2*)&vproj[(size_t)(b * 512 + k0 + kk) * 256 + u0 + uu2];
      vpS[kk * 33 + uu2] = v2.x; vpS[kk * 33 + uu2 + 1] = v2.y;
    }

    // k-invariant Wal build octets (f32-expanded, 16 VGPR)
    float wl0[8], wl1[8];
    {
      const bf16x8 w0 = *(const bf16x8*)&WalF[((size_t)(uc * 32 + c8) * 32 + uu) * 8];
      const bf16x8 w1 = *(const bf16x8*)&WalF[((size_t)(uc * 32 + c8 + 16) * 32 + uu) * 8];
#pragma unroll
      for (int j = 0; j < 8; ++j) { wl0[j] = bf2f(w0[j]); wl1[j] = bf2f(w1[j]); }
    }

    // persistent A-fragments (128 VGPR), pinned against rematerialization
    const short* qbase = qpF + (size_t)b * 131072;
    Frag qa[4][8];
#pragma unroll
    for (int qg = 0; qg < 4; ++qg)
#pragma unroll
      for (int ks = 0; ks < 8; ++ks) {
        qa[qg][ks].v = *(const bf16x8*)&qbase[(((size_t)(w * 4 + qg) * 8 + ks) * 64 + lane) * 8];
        asm volatile("" : "+v"(qa[qg][ks].u[0]), "+v"(qa[qg][ks].u[1]),
                          "+v"(qa[qg][ks].u[2]), "+v"(qa[qg][ks].u[3]));
      }

    // per-thread constant addresses (hoisted once)
    const int fb = (l4 * 32 + l15) * 8;                               // frag base
    const float* kq = &kproj[(long)(b * 512 + k0) * 256 + c8 * 8];    // kp base

    // prologue: build W2F[0] for k = k0
    {
      const f32x4 a0 = *(const f32x4*)(kq);
      const f32x4 a1 = *(const f32x4*)(kq + 4);
      const f32x4 b0 = *(const f32x4*)(kq + 128);
      const f32x4 b1 = *(const f32x4*)(kq + 132);
      uint4 st;
      st.x = packrn(wl0[0] * a0[0], wl0[1] * a0[1]);
      st.y = packrn(wl0[2] * a0[2], wl0[3] * a0[3]);
      st.z = packrn(wl0[4] * a1[0], wl0[5] * a1[1]);
      st.w = packrn(wl0[6] * a1[2], wl0[7] * a1[3]);
      *(uint4*)&W2Fp[(c8 * 32 + uu) * 8] = st;
      st.x = packrn(wl1[0] * b0[0], wl1[1] * b0[1]);
      st.y = packrn(wl1[2] * b0[2], wl1[3] * b0[3]);
      st.z = packrn(wl1[4] * b1[0], wl1[5] * b1[1]);
      st.w = packrn(wl1[6] * b1[2], wl1[7] * b1[3]);
      *(uint4*)&W2Fp[((c8 + 16) * 32 + uu) * 8] = st;
    }
    __syncthreads();

    const f32x4 z4 = {0.f, 0.f, 0.f, 0.f};
    f32x4 acc[4][2] = {z4, z4, z4, z4, z4, z4, z4, z4};

#pragma unroll 1
    for (int kk = 0; kk < 32; ++kk) {
      const int cs = kk & 1, ss = kk % 3;

      // issue next k's kp loads early (hidden under MFMA)
      f32x4 a0, a1, b0, b1;
      if (kk < 31) {
        const float* kn = kq + (size_t)(kk + 1) * 256;
        a0 = *(const f32x4*)(kn);
        a1 = *(const f32x4*)(kn + 4);
        b0 = *(const f32x4*)(kn + 128);
        b1 = *(const f32x4*)(kn + 132);
      }

      f32x4 lg[4][2] = {z4, z4, z4, z4, z4, z4, z4, z4};
#pragma unroll
      for (int ks = 0; ks < 8; ++ks) {
        const bf16x8 f0 = *(const bf16x8*)&W2Fp[cs * 8192 + fb + ks * 1024];
        const bf16x8 f1 = *(const bf16x8*)&W2Fp[cs * 8192 + fb + ks * 1024 + 128];
#pragma unroll
        for (int qg = 0; qg < 4; ++qg) {
          lg[qg][0] = __builtin_amdgcn_mfma_f32_16x16x32_bf16(qa[qg][ks].v, f0, lg[qg][0], 0, 0, 0);
          lg[qg][1] = __builtin_amdgcn_mfma_f32_16x16x32_bf16(qa[qg][ks].v, f1, lg[qg][1], 0, 0, 0);
        }
      }
      // pin MFMA results into arch VGPRs (prevent AGPR residency -> shuttles)
#pragma unroll
      for (int qg = 0; qg < 4; ++qg)
        asm volatile("" : "+v"(lg[qg][0]), "+v"(lg[qg][1]));

      // build next slot (slot read last at kk-1, barrier between)
      if (kk < 31) {
        uint4 st;
        st.x = packrn(wl0[0] * a0[0], wl0[1] * a0[1]);
        st.y = packrn(wl0[2] * a0[2], wl0[3] * a0[3]);
        st.z = packrn(wl0[4] * a1[0], wl0[5] * a1[1]);
        st.w = packrn(wl0[6] * a1[2], wl0[7] * a1[3]);
        *(uint4*)&W2Fp[(cs ^ 1) * 8192 + (c8 * 32 + uu) * 8] = st;
        st.x = packrn(wl1[0] * b0[0], wl1[1] * b0[1]);
        st.y = packrn(wl1[2] * b0[2], wl1[3] * b0[3]);
        st.z = packrn(wl1[4] * b1[0], wl1[5] * b1[1]);
        st.w = packrn(wl1[6] * b1[2], wl1[7] * b1[3]);
        *(uint4*)&W2Fp[(cs ^ 1) * 8192 + ((c8 + 16) * 32 + uu) * 8] = st;
      }

      // stats: M = max x (tree), p = x*exp(x), S = sum|p|; shfl reduce,
      // then one atomic per u from l4==0 lanes.
      float Mv[2], Sv[2];
#pragma unroll
      for (int ug = 0; ug < 2; ++ug) {
        const float m0q = fmaxf(fmaxf(lg[0][ug][0], lg[0][ug][1]), fmaxf(lg[0][ug][2], lg[0][ug][3]));
        const float m1q = fmaxf(fmaxf(lg[1][ug][0], lg[1][ug][1]), fmaxf(lg[1][ug][2], lg[1][ug][3]));
        const float m2q = fmaxf(fmaxf(lg[2][ug][0], lg[2][ug][1]), fmaxf(lg[2][ug][2], lg[2][ug][3]));
        const float m3q = fmaxf(fmaxf(lg[3][ug][0], lg[3][ug][1]), fmaxf(lg[3][ug][2], lg[3][ug][3]));
        float m = fmaxf(fmaxf(m0q, m1q), fmaxf(m2q, m3q));
        float sq[4];
#pragma unroll
        for (int qg = 0; qg < 4; ++qg) {
          float p0 = lg[qg][ug][0] * __expf(lg[qg][ug][0]);
          float p1 = lg[qg][ug][1] * __expf(lg[qg][ug][1]);
          float p2 = lg[qg][ug][2] * __expf(lg[qg][ug][2]);
          float p3 = lg[qg][ug][3] * __expf(lg[qg][ug][3]);
          lg[qg][ug][0] = p0; lg[qg][ug][1] = p1;
          lg[qg][ug][2] = p2; lg[qg][ug][3] = p3;
          sq[qg] = (fabsf(p0) + fabsf(p1)) + (fabsf(p2) + fabsf(p3));
        }
        float s = (sq[0] + sq[1]) + (sq[2] + sq[3]);
        m = fmaxf(m, __shfl_xor(m, 16));
        m = fmaxf(m, __shfl_xor(m, 32));
        s += __shfl_xor(s, 16);
        s += __shfl_xor(s, 32);
        Mv[ug] = m; Sv[ug] = s;
      }
      if (l4 == 0) {
        atomicMax(&statM[ss * 32 + l15],      encM(Mv[0]));
        atomicMax(&statM[ss * 32 + 16 + l15], encM(Mv[1]));
        atomicAdd(&statS[ss * 32 + l15],      Sv[0]);
        atomicAdd(&statS[ss * 32 + 16 + l15], Sv[1]);
      }
      __syncthreads();

      // per-lane g + apply (rcp: err ~1e-7, proven within tolerance)
#pragma unroll
      for (int ug = 0; ug < 2; ++ug) {
        const int ui = ug * 16 + l15;
        const float M = decM(statM[ss * 32 + ui]);
        const float S = statS[ss * 32 + ui];
        const float em = __expf(-M);
        const float g = vpS[kk * 33 + ui] * em * __builtin_amdgcn_rcpf(fmaf(S, em, 1.0f));
#pragma unroll
        for (int qg = 0; qg < 4; ++qg)
#pragma unroll
          for (int i = 0; i < 4; ++i)
            acc[qg][ug][i] = fmaf(g, lg[qg][ug][i], acc[qg][ug][i]);
      }
      // pin accumulators into arch VGPRs as well
#pragma unroll
      for (int qg = 0; qg < 4; ++qg)
        asm volatile("" : "+v"(acc[qg][0]), "+v"(acc[qg][1]));

      // reset slot (kk+2)%3 (next used at kk+2; barrier(kk+1) separates)
      const int rs = (kk + 2) % 3;
      if (tid < 32) { statM[rs * 32 + tid] = 0u; statS[rs * 32 + tid] = 0.f; }
    }

#pragma unroll
    for (int qg = 0; qg < 4; ++qg)
#pragma unroll
      for (int ug = 0; ug < 2; ++ug)
#pragma unroll
        for (int i = 0; i < 4; ++i)
          atomicAdd(&vsum[(size_t)(b * 512 + w * 64 + qg * 16 + l4 * 4 + i) * 256 +
                          u0 + ug * 16 + l15],
                    acc[qg][ug][i]);
  }
  grid.sync();

  // ---------------- PHASE 3: out += vsum x Wvo^T (split-K x4) ----------------
  {
    float* As = (float*)(smem + half * 6656);
    float* Ws = (float*)(smem + half * 6656 + 2304);
    const int mt = vb >> 4, ut = (vb >> 2) & 3, kseg = vb & 3;
    const int m0 = mt * 32, u0 = ut * 64;
    float c[2][4] = {};
    gemm32_body(vsum, Wvo, As, Ws, m0, u0, kseg * 64, kseg * 64 + 64, t, c);
    const int tx4 = (t & 15) * 4, ty2 = (t >> 4) * 2;
#pragma unroll
    for (int i = 0; i < 2; ++i)
#pragma unroll
      for (int j = 0; j < 4; ++j)
        atomicAdd(&out[(size_t)(m0 + ty2 + i) * 256 + u0 + tx4 + j], c[i][j]);
  }
}

extern "C" void kernel_launch(void* const* d_in, const int* in_sizes, int n_in,
                              void* d_out, int out_size, void* d_ws, size_t ws_size,
                              hipStream_t stream) {
  const float* query = (const float*)d_in[0];
  const float* key   = (const float*)d_in[1];
  const float* value = (const float*)d_in[2];
  const float* Wk    = (const float*)d_in[3];
  const float* Wq    = (const float*)d_in[4];
  const float* Wva   = (const float*)d_in[5];
  const float* Wal   = (const float*)d_in[6];
  const float* Wvo   = (const float*)d_in[7];
  float* ws = (float*)d_ws;

  float* kproj = ws;                        // 262144 f32
  float* vproj = kproj + 262144;
  float* vsum  = vproj + 262144;
  short* qpF   = (short*)(vsum + 262144);   // 262144 bf16, A-frag-major
  short* WalF  = qpF + 262144;              // 65536 bf16, frag-major
  float* out   = (float*)d_out;

  void* args[] = {
      (void*)&query, (void*)&key, (void*)&value, (void*)&Wk, (void*)&Wq,
      (void*)&Wva, (void*)&Wal, (void*)&Wvo,
      (void*)&kproj, (void*)&vproj, (void*)&vsum, (void*)&qpF, (void*)&WalF,
      (void*)&out};
  hipLaunchCooperativeKernel((const void*)fused, dim3(256), dim3(512), args, 0,
                             stream);
}

// Round 8
// 186.414 us; speedup vs baseline: 1.5296x; 1.5296x over previous
//
#include <hip/hip_runtime.h>
#include <cstdint>

// B=2, Q=512, K=512, T=256 (fp32 in/out).
// R15: R13 (best, 191.9us) + two kernelC scheduling edits:
//  (1) W2F build moved BEFORE the lg pins (volatile-asm fence) so its
//      independent VALU/ds_writes co-issue under the MFMA shadow;
//  (2) max3-shaped max reductions (v_max3_f32 fusion).
// kernelC otherwise EXACT R11; proj3/gemm_out exact R13.
//   p = x*exp(x); M = max_q x, S = sum_q |p|; acc += p * g,
//   g = vproj*e^-M / (S*e^-M + 1).

typedef short bf16x8 __attribute__((ext_vector_type(8)));   // 8 bf16 = 4 VGPR
typedef float f32x4  __attribute__((ext_vector_type(4)));   // MFMA C/D frag

__device__ inline float bf2f(short s) {
  return __uint_as_float(((unsigned)(unsigned short)s) << 16);
}
// f32 pair -> packed bf16 (round-half-up), low short = lo
__device__ inline unsigned packrn(float lo, float hi) {
  return __builtin_amdgcn_perm(__float_as_uint(hi) + 0x8000u,
                               __float_as_uint(lo) + 0x8000u, 0x07060302u);
}
// monotone (unsigned) encoding of f32 for atomic max; 0 == "-infinity" sentinel
__device__ inline unsigned encM(float f) {
  unsigned k = (unsigned)__float_as_int(f);
  return (k & 0x80000000u) ? ~k : (k | 0x80000000u);
}
__device__ inline float decM(unsigned k) {
  int i = (k & 0x80000000u) ? (int)(k ^ 0x80000000u) : (int)~k;
  return __int_as_float(i);
}

// GEMM body, 32x64 tile, 256 thr, prefetch-pipelined. W row-major
// (transposed through LDS). Computes c[2][4]: rows m0+ty2+{0,1}, cols
// u0+tx4+{0..3}, over K range [K0,K1).
#define GEMM_BODY32(X, W, K0, K1)                                               \
  __shared__ __align__(16) float As[16][36];                                    \
  __shared__ __align__(16) float Ws[16][68];                                    \
  const int tid = threadIdx.x;                                                  \
  const int tx4 = (tid & 15) * 4;                                               \
  const int ty2 = (tid >> 4) * 2;                                               \
  const int m0 = blockIdx.x * 32, u0 = blockIdx.y * 64;                         \
  const int lmi = tid >> 2, lc4 = (tid & 3) * 4;                                \
  const bool hasA = tid < 128;                                                  \
  float4 xa, wb;                                                                \
  if (hasA) xa = *(const float4*)&(X)[(size_t)(m0 + lmi) * 256 + (K0) + lc4];   \
  wb = *(const float4*)&(W)[(size_t)(u0 + lmi) * 256 + (K0) + lc4];             \
  float c[2][4] = {};                                                           \
  _Pragma("unroll 1")                                                           \
  for (int t0 = (K0); t0 < (K1); t0 += 16) {                                    \
    __syncthreads();                                                            \
    if (hasA) {                                                                 \
      As[lc4 + 0][lmi] = xa.x; As[lc4 + 1][lmi] = xa.y;                         \
      As[lc4 + 2][lmi] = xa.z; As[lc4 + 3][lmi] = xa.w;                         \
    }                                                                           \
    Ws[lc4 + 0][lmi] = wb.x; Ws[lc4 + 1][lmi] = wb.y;                           \
    Ws[lc4 + 2][lmi] = wb.z; Ws[lc4 + 3][lmi] = wb.w;                           \
    __syncthreads();                                                            \
    if (t0 + 16 < (K1)) {                                                       \
      if (hasA) xa = *(const float4*)&(X)[(size_t)(m0 + lmi) * 256 + t0 + 16 + lc4]; \
      wb = *(const float4*)&(W)[(size_t)(u0 + lmi) * 256 + t0 + 16 + lc4];      \
    }                                                                           \
    _Pragma("unroll")                                                           \
    for (int t = 0; t < 16; ++t) {                                              \
      const float2 a = *(const float2*)&As[t][ty2];                             \
      const float4 w = *(const float4*)&Ws[t][tx4];                             \
      c[0][0] += a.x*w.x; c[0][1] += a.x*w.y; c[0][2] += a.x*w.z; c[0][3] += a.x*w.w; \
      c[1][0] += a.y*w.x; c[1][1] += a.y*w.y; c[1][2] += a.y*w.z; c[1][3] += a.y*w.w; \
    }                                                                           \
  }

// Projections + aux. z=0 key->kproj(f32), z=1 value->vproj(f32),
// z=2 query->qpF (bf16 A-frag-major), z=3: WalF build + vsum/out zero.
__global__ __launch_bounds__(256) void proj3(
    const float* __restrict__ key, const float* __restrict__ value,
    const float* __restrict__ query, const float* __restrict__ Wk,
    const float* __restrict__ Wq, const float* __restrict__ Wva,
    const float* __restrict__ Wal, float* __restrict__ kproj,
    float* __restrict__ vproj, short* __restrict__ qpF,
    short* __restrict__ WalF, float* __restrict__ vsum,
    float* __restrict__ outz)
{
  const int z = blockIdx.z;
  if (z == 3) {
    const int p = blockIdx.x * 4 + blockIdx.y;    // 0..127, use 0..63
    if (p >= 64) return;
    const int t256 = threadIdx.x;
    // WalF: frag-major bf16 copy of Wal; 1024 shorts per block
#pragma unroll
    for (int e = 0; e < 4; ++e) {
      const int d = p * 1024 + t256 * 4 + e;
      const int j = d & 7, uu = (d >> 3) & 31, c8g = d >> 8;
      const int ucx = c8g >> 5, cc = c8g & 31;
      const float v = Wal[(ucx * 32 + uu) * 256 + cc * 8 + j];
      WalF[d] = (short)packrn(v, v);
    }
    // vsum + out zero: 4096 floats each per block
    float4* vz = (float4*)(vsum + p * 4096);
    float4* oz = (float4*)(outz + p * 4096);
#pragma unroll
    for (int e = 0; e < 4; ++e) {
      vz[t256 * 4 + e] = make_float4(0.f, 0.f, 0.f, 0.f);
      oz[t256 * 4 + e] = make_float4(0.f, 0.f, 0.f, 0.f);
    }
    return;
  }
  const float* X = (z == 0) ? key : (z == 1) ? value : query;
  const float* W = (z == 0) ? Wk  : (z == 1) ? Wva   : Wq;
  GEMM_BODY32(X, W, 0, 256);
  if (z == 2) {
    const int tbase = u0 + tx4;               // t coordinate
    const int ks = tbase >> 5, l4f = (tbase & 31) >> 3, j0 = tbase & 7;
#pragma unroll
    for (int i = 0; i < 2; ++i) {
      const int m = m0 + ty2 + i;             // global row = b*512 + q
      const int bb = m >> 9, q = m & 511;
      const int g = q >> 4, l15q = q & 15;
      const size_t idx = ((size_t)(((bb * 32 + g) * 8 + ks) * 64) + l4f * 16 + l15q) * 8 + j0;
      uint2 s; s.x = packrn(c[i][0], c[i][1]); s.y = packrn(c[i][2], c[i][3]);
      *(uint2*)&qpF[idx] = s;
    }
  } else {
    float* C = (z == 0) ? kproj : vproj;
#pragma unroll
    for (int i = 0; i < 2; ++i)
      *(float4*)&C[(size_t)(m0 + ty2 + i) * 256 + u0 + tx4] =
          make_float4(c[i][0], c[i][1], c[i][2], c[i][3]);
  }
}

// Final projection: out += vsum x Wvo^T over K half blockIdx.z (split-K).
__global__ __launch_bounds__(256) void gemm_out(
    const float* __restrict__ X, const float* __restrict__ W, float* __restrict__ out)
{
  const int kh = blockIdx.z * 128;
  GEMM_BODY32(X, W, kh, kh + 128);
#pragma unroll
  for (int i = 0; i < 2; ++i)
#pragma unroll
    for (int j = 0; j < 4; ++j)
      atomicAdd(&out[(size_t)(m0 + ty2 + i) * 256 + u0 + tx4 + j], c[i][j]);
}

union Frag { bf16x8 v; unsigned u[4]; };

// ---------------------------------------------------------------------------
// kernelC: grid (16 kt, 8 uc, 2 b), 512 thr = 8 waves; wave w: q in
// [w*64, w*64+64), full 32-u chunk. qa (64q x 256t bf16 = 128 VGPR) pinned.
// Per k (ONE barrier): MFMA from W2F[k&1]; build W2F[(k+1)&1] (BEFORE the lg
// pins so its VALU hides under MFMA); shfl stats (max3-shaped) + l4==0 LDS
// atomics (slot k%3); barrier; per-lane g (rcp); apply; reset slot (k+2)%3.
// lg/acc pinned to "v" class (no AGPR shuttling).
// ---------------------------------------------------------------------------
__global__ __launch_bounds__(512, 2) void kernelC(
    const short* __restrict__ qpF, const float* __restrict__ kproj,
    const float* __restrict__ vproj, const short* __restrict__ WalF,
    float* __restrict__ vsum)
{
  __shared__ __align__(16) short W2F[2][8192];  // 2 x 16 KB, [c8][u][8]
  __shared__ float vpS[32 * 33];                // vproj tile [kk][u], padded
  __shared__ unsigned statM[96];                // 3 slots x 32 u (encoded max)
  __shared__ float statS[96];                   // 3 slots x 32 u

  const int kt = blockIdx.x, uc = blockIdx.y, b = blockIdx.z;
  const int u0 = uc * 32, k0 = kt * 32;
  const int tid = threadIdx.x;
  const int lane = tid & 63, w = tid >> 6;      // w in [0,8)
  const int l15 = lane & 15, l4 = lane >> 4;
  const int uu = tid & 31, c8 = tid >> 5;       // build mapping: c8 and c8+16

  if (tid < 96) { statM[tid] = 0u; statS[tid] = 0.f; }
  {
    const int kk = tid >> 4, uu2 = (tid & 15) * 2;
    const float2 v2 = *(const float2*)&vproj[(size_t)(b * 512 + k0 + kk) * 256 + u0 + uu2];
    vpS[kk * 33 + uu2] = v2.x; vpS[kk * 33 + uu2 + 1] = v2.y;
  }

  // k-invariant Wal build octets (f32-expanded, 16 VGPR)
  float wl0[8], wl1[8];
  {
    const bf16x8 w0 = *(const bf16x8*)&WalF[((size_t)(uc * 32 + c8) * 32 + uu) * 8];
    const bf16x8 w1 = *(const bf16x8*)&WalF[((size_t)(uc * 32 + c8 + 16) * 32 + uu) * 8];
#pragma unroll
    for (int j = 0; j < 8; ++j) { wl0[j] = bf2f(w0[j]); wl1[j] = bf2f(w1[j]); }
  }

  // persistent A-fragments (128 VGPR), pinned against rematerialization
  const short* qbase = qpF + (size_t)b * 131072;
  Frag qa[4][8];
#pragma unroll
  for (int qg = 0; qg < 4; ++qg)
#pragma unroll
    for (int ks = 0; ks < 8; ++ks) {
      qa[qg][ks].v = *(const bf16x8*)&qbase[(((size_t)(w * 4 + qg) * 8 + ks) * 64 + lane) * 8];
      asm volatile("" : "+v"(qa[qg][ks].u[0]), "+v"(qa[qg][ks].u[1]),
                        "+v"(qa[qg][ks].u[2]), "+v"(qa[qg][ks].u[3]));
    }

  // per-thread constant addresses (hoisted once)
  const int fb = (l4 * 32 + l15) * 8;                               // frag base
  const float* kq = &kproj[(long)(b * 512 + k0) * 256 + c8 * 8];    // kp base

  // prologue: build W2F[0] for k = k0
  {
    const f32x4 a0 = *(const f32x4*)(kq);
    const f32x4 a1 = *(const f32x4*)(kq + 4);
    const f32x4 b0 = *(const f32x4*)(kq + 128);
    const f32x4 b1 = *(const f32x4*)(kq + 132);
    uint4 st;
    st.x = packrn(wl0[0] * a0[0], wl0[1] * a0[1]);
    st.y = packrn(wl0[2] * a0[2], wl0[3] * a0[3]);
    st.z = packrn(wl0[4] * a1[0], wl0[5] * a1[1]);
    st.w = packrn(wl0[6] * a1[2], wl0[7] * a1[3]);
    *(uint4*)&W2F[0][(c8 * 32 + uu) * 8] = st;
    st.x = packrn(wl1[0] * b0[0], wl1[1] * b0[1]);
    st.y = packrn(wl1[2] * b0[2], wl1[3] * b0[3]);
    st.z = packrn(wl1[4] * b1[0], wl1[5] * b1[1]);
    st.w = packrn(wl1[6] * b1[2], wl1[7] * b1[3]);
    *(uint4*)&W2F[0][((c8 + 16) * 32 + uu) * 8] = st;
  }
  __syncthreads();

  const f32x4 z4 = {0.f, 0.f, 0.f, 0.f};
  f32x4 acc[4][2] = {z4, z4, z4, z4, z4, z4, z4, z4};

#pragma unroll 1
  for (int kk = 0; kk < 32; ++kk) {
    const int cs = kk & 1, ss = kk % 3;

    // issue next k's kp loads early (hidden under MFMA)
    f32x4 a0, a1, b0, b1;
    if (kk < 31) {
      const float* kn = kq + (size_t)(kk + 1) * 256;
      a0 = *(const f32x4*)(kn);
      a1 = *(const f32x4*)(kn + 4);
      b0 = *(const f32x4*)(kn + 128);
      b1 = *(const f32x4*)(kn + 132);
    }

    f32x4 lg[4][2] = {z4, z4, z4, z4, z4, z4, z4, z4};
#pragma unroll
    for (int ks = 0; ks < 8; ++ks) {
      const bf16x8 f0 = *(const bf16x8*)&W2F[cs][fb + ks * 1024];
      const bf16x8 f1 = *(const bf16x8*)&W2F[cs][fb + ks * 1024 + 128];
#pragma unroll
      for (int qg = 0; qg < 4; ++qg) {
        lg[qg][0] = __builtin_amdgcn_mfma_f32_16x16x32_bf16(qa[qg][ks].v, f0, lg[qg][0], 0, 0, 0);
        lg[qg][1] = __builtin_amdgcn_mfma_f32_16x16x32_bf16(qa[qg][ks].v, f1, lg[qg][1], 0, 0, 0);
      }
    }

    // build next slot FIRST (independent of lg: only prefetched kp + wl) so
    // the scheduler can co-issue its VALU/ds_writes under the MFMA shadow.
    // (write-after-read safe: slot read last at kk-1, barrier between)
    if (kk < 31) {
      uint4 st;
      st.x = packrn(wl0[0] * a0[0], wl0[1] * a0[1]);
      st.y = packrn(wl0[2] * a0[2], wl0[3] * a0[3]);
      st.z = packrn(wl0[4] * a1[0], wl0[5] * a1[1]);
      st.w = packrn(wl0[6] * a1[2], wl0[7] * a1[3]);
      *(uint4*)&W2F[cs ^ 1][(c8 * 32 + uu) * 8] = st;
      st.x = packrn(wl1[0] * b0[0], wl1[1] * b0[1]);
      st.y = packrn(wl1[2] * b0[2], wl1[3] * b0[3]);
      st.z = packrn(wl1[4] * b1[0], wl1[5] * b1[1]);
      st.w = packrn(wl1[6] * b1[2], wl1[7] * b1[3]);
      *(uint4*)&W2F[cs ^ 1][((c8 + 16) * 32 + uu) * 8] = st;
    }

    // pin MFMA results into arch VGPRs (prevent AGPR residency -> shuttles)
#pragma unroll
    for (int qg = 0; qg < 4; ++qg)
      asm volatile("" : "+v"(lg[qg][0]), "+v"(lg[qg][1]));

    // stats: M = max x (max3-shaped tree), p = x*exp(x), S = sum|p|; shfl
    // reduce across the 4 lane-groups, then one atomic per u from l4==0.
    float Mv[2], Sv[2];
#pragma unroll
    for (int ug = 0; ug < 2; ++ug) {
      // per-qg max4 as max3+max (v_max3_f32 fusion)
      const float m0q = fmaxf(fmaxf(fmaxf(lg[0][ug][0], lg[0][ug][1]), lg[0][ug][2]), lg[0][ug][3]);
      const float m1q = fmaxf(fmaxf(fmaxf(lg[1][ug][0], lg[1][ug][1]), lg[1][ug][2]), lg[1][ug][3]);
      const float m2q = fmaxf(fmaxf(fmaxf(lg[2][ug][0], lg[2][ug][1]), lg[2][ug][2]), lg[2][ug][3]);
      const float m3q = fmaxf(fmaxf(fmaxf(lg[3][ug][0], lg[3][ug][1]), lg[3][ug][2]), lg[3][ug][3]);
      float m = fmaxf(fmaxf(fmaxf(m0q, m1q), m2q), m3q);
      float sq[4];
#pragma unroll
      for (int qg = 0; qg < 4; ++qg) {
        float p0 = lg[qg][ug][0] * __expf(lg[qg][ug][0]);
        float p1 = lg[qg][ug][1] * __expf(lg[qg][ug][1]);
        float p2 = lg[qg][ug][2] * __expf(lg[qg][ug][2]);
        float p3 = lg[qg][ug][3] * __expf(lg[qg][ug][3]);
        lg[qg][ug][0] = p0; lg[qg][ug][1] = p1;
        lg[qg][ug][2] = p2; lg[qg][ug][3] = p3;
        sq[qg] = (fabsf(p0) + fabsf(p1)) + (fabsf(p2) + fabsf(p3));
      }
      float s = (sq[0] + sq[1]) + (sq[2] + sq[3]);
      m = fmaxf(m, __shfl_xor(m, 16));
      m = fmaxf(m, __shfl_xor(m, 32));
      s += __shfl_xor(s, 16);
      s += __shfl_xor(s, 32);
      Mv[ug] = m; Sv[ug] = s;
    }
    if (l4 == 0) {
      atomicMax(&statM[ss * 32 + l15],      encM(Mv[0]));
      atomicMax(&statM[ss * 32 + 16 + l15], encM(Mv[1]));
      atomicAdd(&statS[ss * 32 + l15],      Sv[0]);
      atomicAdd(&statS[ss * 32 + 16 + l15], Sv[1]);
    }
    __syncthreads();

    // per-lane g + apply (rcp: err ~1e-7, proven within tolerance)
#pragma unroll
    for (int ug = 0; ug < 2; ++ug) {
      const int ui = ug * 16 + l15;
      const float M = decM(statM[ss * 32 + ui]);
      const float S = statS[ss * 32 + ui];
      const float em = __expf(-M);
      const float g = vpS[kk * 33 + ui] * em * __builtin_amdgcn_rcpf(fmaf(S, em, 1.0f));
#pragma unroll
      for (int qg = 0; qg < 4; ++qg)
#pragma unroll
        for (int i = 0; i < 4; ++i)
          acc[qg][ug][i] = fmaf(g, lg[qg][ug][i], acc[qg][ug][i]);
    }
    // pin accumulators into arch VGPRs as well
#pragma unroll
    for (int qg = 0; qg < 4; ++qg)
      asm volatile("" : "+v"(acc[qg][0]), "+v"(acc[qg][1]));

    // reset slot (kk+2)%3 (next used at kk+2; barrier(kk+1) separates)
    const int rs = (kk + 2) % 3;
    if (tid < 32) { statM[rs * 32 + tid] = 0u; statS[rs * 32 + tid] = 0.f; }
  }

#pragma unroll
  for (int qg = 0; qg < 4; ++qg)
#pragma unroll
    for (int ug = 0; ug < 2; ++ug)
#pragma unroll
      for (int i = 0; i < 4; ++i)
        atomicAdd(&vsum[(size_t)(b * 512 + w * 64 + qg * 16 + l4 * 4 + i) * 256 +
                        u0 + ug * 16 + l15],
                  acc[qg][ug][i]);
}

extern "C" void kernel_launch(void* const* d_in, const int* in_sizes, int n_in,
                              void* d_out, int out_size, void* d_ws, size_t ws_size,
                              hipStream_t stream) {
  const float* query = (const float*)d_in[0];
  const float* key   = (const float*)d_in[1];
  const float* value = (const float*)d_in[2];
  const float* Wk    = (const float*)d_in[3];
  const float* Wq    = (const float*)d_in[4];
  const float* Wva   = (const float*)d_in[5];
  const float* Wal   = (const float*)d_in[6];
  const float* Wvo   = (const float*)d_in[7];
  float* ws = (float*)d_ws;

  float* kproj = ws;                        // 262144 f32
  float* vproj = kproj + 262144;
  float* vsum  = vproj + 262144;
  short* qpF   = (short*)(vsum + 262144);   // 262144 bf16, A-frag-major
  short* WalF  = qpF + 262144;              // 65536 bf16, frag-major
  float* out   = (float*)d_out;

  proj3<<<dim3(32, 4, 4), 256, 0, stream>>>(key, value, query, Wk, Wq, Wva, Wal,
                                            kproj, vproj, qpF, WalF, vsum, out);
  kernelC<<<dim3(16, 8, 2), 512, 0, stream>>>(qpF, kproj, vproj, WalF, vsum);
  gemm_out<<<dim3(32, 4, 2), 256, 0, stream>>>(vsum, Wvo, out);
}

// Round 9
// 176.444 us; speedup vs baseline: 1.6160x; 1.0565x over previous
//
#include <hip/hip_runtime.h>
#include <cstdint>

// B=2, Q=512, K=512, T=256 (fp32 in/out).
// R16: kernelC moved to mfma_f32_32x32x16_bf16 (C col=lane&31 -> u):
//  - shfl count 8->2 per thread/kk (shfls ride the DS pipe), one g-chain
//  - MFMA instr 64->32 per wave/kk at better FLOP/cyc
//  - e^M identity: g = vproj/(S + e^M), e^M = max_q e^x (computed anyway);
//    statM stores raw float bits (positive floats are unsigned-monotone).
// proj3 z=2 writes qpF in 32x32 A-frag layout; WalF is a plain bf16 copy.
// proj3/gemm_out GEMM bodies exact R15.

typedef short bf16x8 __attribute__((ext_vector_type(8)));   // 8 bf16 = 4 VGPR
typedef float f32x4  __attribute__((ext_vector_type(4)));
typedef float f32x16 __attribute__((ext_vector_type(16)));  // 32x32 C/D frag

__device__ inline float bf2f(short s) {
  return __uint_as_float(((unsigned)(unsigned short)s) << 16);
}
// f32 pair -> packed bf16 (round-half-up), low short = lo
__device__ inline unsigned packrn(float lo, float hi) {
  return __builtin_amdgcn_perm(__float_as_uint(hi) + 0x8000u,
                               __float_as_uint(lo) + 0x8000u, 0x07060302u);
}

// GEMM body, 32x64 tile, 256 thr, prefetch-pipelined (exact R15).
#define GEMM_BODY32(X, W, K0, K1)                                               \
  __shared__ __align__(16) float As[16][36];                                    \
  __shared__ __align__(16) float Ws[16][68];                                    \
  const int tid = threadIdx.x;                                                  \
  const int tx4 = (tid & 15) * 4;                                               \
  const int ty2 = (tid >> 4) * 2;                                               \
  const int m0 = blockIdx.x * 32, u0 = blockIdx.y * 64;                         \
  const int lmi = tid >> 2, lc4 = (tid & 3) * 4;                                \
  const bool hasA = tid < 128;                                                  \
  float4 xa, wb;                                                                \
  if (hasA) xa = *(const float4*)&(X)[(size_t)(m0 + lmi) * 256 + (K0) + lc4];   \
  wb = *(const float4*)&(W)[(size_t)(u0 + lmi) * 256 + (K0) + lc4];             \
  float c[2][4] = {};                                                           \
  _Pragma("unroll 1")                                                           \
  for (int t0 = (K0); t0 < (K1); t0 += 16) {                                    \
    __syncthreads();                                                            \
    if (hasA) {                                                                 \
      As[lc4 + 0][lmi] = xa.x; As[lc4 + 1][lmi] = xa.y;                         \
      As[lc4 + 2][lmi] = xa.z; As[lc4 + 3][lmi] = xa.w;                         \
    }                                                                           \
    Ws[lc4 + 0][lmi] = wb.x; Ws[lc4 + 1][lmi] = wb.y;                           \
    Ws[lc4 + 2][lmi] = wb.z; Ws[lc4 + 3][lmi] = wb.w;                           \
    __syncthreads();                                                            \
    if (t0 + 16 < (K1)) {                                                       \
      if (hasA) xa = *(const float4*)&(X)[(size_t)(m0 + lmi) * 256 + t0 + 16 + lc4]; \
      wb = *(const float4*)&(W)[(size_t)(u0 + lmi) * 256 + t0 + 16 + lc4];      \
    }                                                                           \
    _Pragma("unroll")                                                           \
    for (int t = 0; t < 16; ++t) {                                              \
      const float2 a = *(const float2*)&As[t][ty2];                             \
      const float4 w = *(const float4*)&Ws[t][tx4];                             \
      c[0][0] += a.x*w.x; c[0][1] += a.x*w.y; c[0][2] += a.x*w.z; c[0][3] += a.x*w.w; \
      c[1][0] += a.y*w.x; c[1][1] += a.y*w.y; c[1][2] += a.y*w.z; c[1][3] += a.y*w.w; \
    }                                                                           \
  }

// Projections + aux. z=0 key->kproj(f32), z=1 value->vproj(f32),
// z=2 query->qpF (bf16, 32x32 A-frag-major), z=3: WalF copy + vsum/out zero.
__global__ __launch_bounds__(256) void proj3(
    const float* __restrict__ key, const float* __restrict__ value,
    const float* __restrict__ query, const float* __restrict__ Wk,
    const float* __restrict__ Wq, const float* __restrict__ Wva,
    const float* __restrict__ Wal, float* __restrict__ kproj,
    float* __restrict__ vproj, short* __restrict__ qpF,
    short* __restrict__ WalF, float* __restrict__ vsum,
    float* __restrict__ outz)
{
  const int z = blockIdx.z;
  if (z == 3) {
    const int p = blockIdx.x * 4 + blockIdx.y;    // 0..127, use 0..63
    if (p >= 64) return;
    const int t256 = threadIdx.x;
    // WalF: plain row-major bf16 copy of Wal [u][t]
#pragma unroll
    for (int e = 0; e < 4; ++e) {
      const int d = p * 1024 + t256 * 4 + e;
      const float v = Wal[d];
      WalF[d] = (short)packrn(v, v);
    }
    // vsum + out zero: 4096 floats each per block
    float4* vz = (float4*)(vsum + p * 4096);
    float4* oz = (float4*)(outz + p * 4096);
#pragma unroll
    for (int e = 0; e < 4; ++e) {
      vz[t256 * 4 + e] = make_float4(0.f, 0.f, 0.f, 0.f);
      oz[t256 * 4 + e] = make_float4(0.f, 0.f, 0.f, 0.f);
    }
    return;
  }
  const float* X = (z == 0) ? key : (z == 1) ? value : query;
  const float* W = (z == 0) ? Wk  : (z == 1) ? Wva   : Wq;
  GEMM_BODY32(X, W, 0, 256);
  if (z == 2) {
    // 32x32x16 A-frag layout: element (q,t) -> g32=q>>5, row=q&31,
    // ts=t>>4, khalf=(t>>3)&1, j=t&7, lane=khalf*32+row.
    const int tbase = u0 + tx4;                   // t coordinate (4-aligned)
    const int ts = tbase >> 4, khalf = (tbase >> 3) & 1, j0 = tbase & 7;
#pragma unroll
    for (int i = 0; i < 2; ++i) {
      const int m = m0 + ty2 + i;                 // global row = b*512 + q
      const int bb = m >> 9, q = m & 511;
      const int g32 = q >> 5, row = q & 31;
      const int lane = khalf * 32 + row;
      const size_t idx =
          (((size_t)(bb * 16 + g32) * 16 + ts) * 64 + lane) * 8 + j0;
      uint2 s; s.x = packrn(c[i][0], c[i][1]); s.y = packrn(c[i][2], c[i][3]);
      *(uint2*)&qpF[idx] = s;
    }
  } else {
    float* C = (z == 0) ? kproj : vproj;
#pragma unroll
    for (int i = 0; i < 2; ++i)
      *(float4*)&C[(size_t)(m0 + ty2 + i) * 256 + u0 + tx4] =
          make_float4(c[i][0], c[i][1], c[i][2], c[i][3]);
  }
}

// Final projection: out += vsum x Wvo^T over K half blockIdx.z (split-K).
__global__ __launch_bounds__(256) void gemm_out(
    const float* __restrict__ X, const float* __restrict__ W, float* __restrict__ out)
{
  const int kh = blockIdx.z * 128;
  GEMM_BODY32(X, W, kh, kh + 128);
#pragma unroll
  for (int i = 0; i < 2; ++i)
#pragma unroll
    for (int j = 0; j < 4; ++j)
      atomicAdd(&out[(size_t)(m0 + ty2 + i) * 256 + u0 + tx4 + j], c[i][j]);
}

union Frag  { bf16x8 v; unsigned u[4]; };
union Acc16 { f32x16 v; f32x4 f4[4]; };

// ---------------------------------------------------------------------------
// kernelC: grid (16 kt, 8 uc, 2 b), 512 thr = 8 waves; wave w: q in
// [w*64, w*64+64) as 2x 32x32 MFMA tiles, full 32-u chunk. qa (128 VGPR)
// pinned. Per k (ONE barrier): 32x MFMA 32x32x16 from W2F[k&1]; build
// W2F[(k+1)&1]; per-lane stats over own 32 q (e^M identity), 1 shfl_xor(32),
// lane<32 atomics (slot k%3); barrier; g = vp/(S+EM) (rcp); apply; reset
// slot (k+2)%3. lg/acc pinned to "v" class (no AGPR shuttling).
// ---------------------------------------------------------------------------
__global__ __launch_bounds__(512, 2) void kernelC(
    const short* __restrict__ qpF, const float* __restrict__ kproj,
    const float* __restrict__ vproj, const short* __restrict__ WalF,
    float* __restrict__ vsum)
{
  __shared__ __align__(16) short W2F[2][8192];  // [cs][(ts*64 + lane)*8]
  __shared__ float vpS[32 * 33];                // vproj tile [kk][u], padded
  __shared__ unsigned statM[96];                // 3 slots x 32 u (float bits of EM)
  __shared__ float statS[96];                   // 3 slots x 32 u

  const int kt = blockIdx.x, uc = blockIdx.y, b = blockIdx.z;
  const int u0 = uc * 32, k0 = kt * 32;
  const int tid = threadIdx.x;
  const int lane = tid & 63, w = tid >> 6;      // w in [0,8)
  const int ul = lane & 31;                     // u column (C: col=lane&31)
  const int tsb = tid >> 5, ub = tid & 31;      // build mapping: (ts, u)

  if (tid < 96) { statM[tid] = 0u; statS[tid] = 0.f; }
  {
    const int kk = tid >> 4, uu2 = (tid & 15) * 2;
    const float2 v2 = *(const float2*)&vproj[(size_t)(b * 512 + k0 + kk) * 256 + u0 + uu2];
    vpS[kk * 33 + uu2] = v2.x; vpS[kk * 33 + uu2 + 1] = v2.y;
  }

  // k-invariant Wal octets for (u=ub, t = tsb*16 + 0..15), f32-expanded
  float wl0[8], wl1[8];
  {
    const bf16x8 w0 = *(const bf16x8*)&WalF[(size_t)(uc * 32 + ub) * 256 + tsb * 16];
    const bf16x8 w1 = *(const bf16x8*)&WalF[(size_t)(uc * 32 + ub) * 256 + tsb * 16 + 8];
#pragma unroll
    for (int j = 0; j < 8; ++j) { wl0[j] = bf2f(w0[j]); wl1[j] = bf2f(w1[j]); }
  }

  // persistent A-fragments (2 q-tiles x 16 t-steps = 128 VGPR), pinned
  const short* qbase = qpF + (size_t)b * 131072;
  Frag qa[2][16];
#pragma unroll
  for (int qt = 0; qt < 2; ++qt)
#pragma unroll
    for (int ts = 0; ts < 16; ++ts) {
      qa[qt][ts].v = *(const bf16x8*)&qbase[(((size_t)(w * 2 + qt) * 16 + ts) * 64 + lane) * 8];
      asm volatile("" : "+v"(qa[qt][ts].u[0]), "+v"(qa[qt][ts].u[1]),
                        "+v"(qa[qt][ts].u[2]), "+v"(qa[qt][ts].u[3]));
    }

  // per-thread constant addresses
  const int fb = lane * 8;                                            // frag base
  const float* kq = &kproj[(long)(b * 512 + k0) * 256 + tsb * 16];    // kp base

  // prologue: build W2F[0] for k = k0 (two octets per thread)
  {
    const f32x4 a0 = *(const f32x4*)(kq);
    const f32x4 a1 = *(const f32x4*)(kq + 4);
    const f32x4 a2 = *(const f32x4*)(kq + 8);
    const f32x4 a3 = *(const f32x4*)(kq + 12);
    uint4 st;
    st.x = packrn(wl0[0] * a0[0], wl0[1] * a0[1]);
    st.y = packrn(wl0[2] * a0[2], wl0[3] * a0[3]);
    st.z = packrn(wl0[4] * a1[0], wl0[5] * a1[1]);
    st.w = packrn(wl0[6] * a1[2], wl0[7] * a1[3]);
    *(uint4*)&W2F[0][(tsb * 64 + ub) * 8] = st;
    st.x = packrn(wl1[0] * a2[0], wl1[1] * a2[1]);
    st.y = packrn(wl1[2] * a2[2], wl1[3] * a2[3]);
    st.z = packrn(wl1[4] * a3[0], wl1[5] * a3[1]);
    st.w = packrn(wl1[6] * a3[2], wl1[7] * a3[3]);
    *(uint4*)&W2F[0][(tsb * 64 + 32 + ub) * 8] = st;
  }
  __syncthreads();

  Acc16 acc[2];
  acc[0].v = 0.f; acc[1].v = 0.f;

#pragma unroll 1
  for (int kk = 0; kk < 32; ++kk) {
    const int cs = kk & 1, ss = kk % 3;

    // issue next k's kp loads early (hidden under MFMA)
    f32x4 a0, a1, a2, a3;
    if (kk < 31) {
      const float* kn = kq + (size_t)(kk + 1) * 256;
      a0 = *(const f32x4*)(kn);
      a1 = *(const f32x4*)(kn + 4);
      a2 = *(const f32x4*)(kn + 8);
      a3 = *(const f32x4*)(kn + 12);
    }

    Acc16 lg[2];
    lg[0].v = 0.f; lg[1].v = 0.f;
#pragma unroll
    for (int ts = 0; ts < 16; ++ts) {
      const bf16x8 f = *(const bf16x8*)&W2F[cs][ts * 512 + fb];
      lg[0].v = __builtin_amdgcn_mfma_f32_32x32x16_bf16(qa[0][ts].v, f, lg[0].v, 0, 0, 0);
      lg[1].v = __builtin_amdgcn_mfma_f32_32x32x16_bf16(qa[1][ts].v, f, lg[1].v, 0, 0, 0);
    }

    // build next slot FIRST (independent of lg) so its VALU/ds_writes
    // co-issue under the MFMA shadow. (slot read last at kk-1, barrier between)
    if (kk < 31) {
      uint4 st;
      st.x = packrn(wl0[0] * a0[0], wl0[1] * a0[1]);
      st.y = packrn(wl0[2] * a0[2], wl0[3] * a0[3]);
      st.z = packrn(wl0[4] * a1[0], wl0[5] * a1[1]);
      st.w = packrn(wl0[6] * a1[2], wl0[7] * a1[3]);
      *(uint4*)&W2F[cs ^ 1][(tsb * 64 + ub) * 8] = st;
      st.x = packrn(wl1[0] * a2[0], wl1[1] * a2[1]);
      st.y = packrn(wl1[2] * a2[2], wl1[3] * a2[3]);
      st.z = packrn(wl1[4] * a3[0], wl1[5] * a3[1]);
      st.w = packrn(wl1[6] * a3[2], wl1[7] * a3[3]);
      *(uint4*)&W2F[cs ^ 1][(tsb * 64 + 32 + ub) * 8] = st;
    }

    // pin MFMA results into arch VGPRs (prevent AGPR residency -> shuttles)
#pragma unroll
    for (int qt = 0; qt < 2; ++qt)
      asm volatile("" : "+v"(lg[qt].f4[0]), "+v"(lg[qt].f4[1]),
                        "+v"(lg[qt].f4[2]), "+v"(lg[qt].f4[3]));

    // stats (e^M identity): e = exp(x), EM = max e, p = x*e, S = sum|p|.
    // Lane owns 32 q values of ONE u column; partner lane^32 has the other
    // 32 q rows of the same u -> single shfl_xor(32) completes the reduce.
    float em[4] = {0.f, 0.f, 0.f, 0.f};
    float sp[4] = {0.f, 0.f, 0.f, 0.f};
#pragma unroll
    for (int qt = 0; qt < 2; ++qt)
#pragma unroll
      for (int r = 0; r < 16; ++r) {
        const float x = lg[qt].f4[r >> 2][r & 3];
        const float e = __expf(x);
        const float p = x * e;
        lg[qt].f4[r >> 2][r & 3] = p;
        em[r & 3] = fmaxf(em[r & 3], e);
        sp[r & 3] += fabsf(p);
      }
    float EM = fmaxf(fmaxf(em[0], em[1]), fmaxf(em[2], em[3]));
    float S  = (sp[0] + sp[1]) + (sp[2] + sp[3]);
    EM = fmaxf(EM, __shfl_xor(EM, 32));
    S += __shfl_xor(S, 32);
    if (lane < 32) {
      atomicMax(&statM[ss * 32 + ul], __float_as_uint(EM));  // EM>0: bits monotone
      atomicAdd(&statS[ss * 32 + ul], S);
    }
    __syncthreads();

    // per-lane g + apply: g = vp / (S + e^M)  (rcp, proven within tolerance)
    {
      const float EMf = __uint_as_float(statM[ss * 32 + ul]);
      const float Sf  = statS[ss * 32 + ul];
      const float g = vpS[kk * 33 + ul] * __builtin_amdgcn_rcpf(Sf + EMf);
#pragma unroll
      for (int qt = 0; qt < 2; ++qt)
#pragma unroll
        for (int r = 0; r < 16; ++r)
          acc[qt].f4[r >> 2][r & 3] =
              fmaf(g, lg[qt].f4[r >> 2][r & 3], acc[qt].f4[r >> 2][r & 3]);
    }
    // pin accumulators into arch VGPRs as well
#pragma unroll
    for (int qt = 0; qt < 2; ++qt)
      asm volatile("" : "+v"(acc[qt].f4[0]), "+v"(acc[qt].f4[1]),
                        "+v"(acc[qt].f4[2]), "+v"(acc[qt].f4[3]));

    // reset slot (kk+2)%3 (next used at kk+2; barrier(kk+1) separates)
    const int rs = (kk + 2) % 3;
    if (tid < 32) { statM[rs * 32 + tid] = 0u; statS[rs * 32 + tid] = 0.f; }
  }

  // epilogue: C row = (r&3) + 8*(r>>2) + 4*(lane>>5), col = ul
#pragma unroll
  for (int qt = 0; qt < 2; ++qt)
#pragma unroll
    for (int r = 0; r < 16; ++r) {
      const int q = w * 64 + qt * 32 + (r & 3) + 8 * (r >> 2) + 4 * (lane >> 5);
      atomicAdd(&vsum[(size_t)(b * 512 + q) * 256 + u0 + ul],
                acc[qt].f4[r >> 2][r & 3]);
    }
}

extern "C" void kernel_launch(void* const* d_in, const int* in_sizes, int n_in,
                              void* d_out, int out_size, void* d_ws, size_t ws_size,
                              hipStream_t stream) {
  const float* query = (const float*)d_in[0];
  const float* key   = (const float*)d_in[1];
  const float* value = (const float*)d_in[2];
  const float* Wk    = (const float*)d_in[3];
  const float* Wq    = (const float*)d_in[4];
  const float* Wva   = (const float*)d_in[5];
  const float* Wal   = (const float*)d_in[6];
  const float* Wvo   = (const float*)d_in[7];
  float* ws = (float*)d_ws;

  float* kproj = ws;                        // 262144 f32
  float* vproj = kproj + 262144;
  float* vsum  = vproj + 262144;
  short* qpF   = (short*)(vsum + 262144);   // 262144 bf16, 32x32 A-frag-major
  short* WalF  = qpF + 262144;              // 65536 bf16, row-major copy
  float* out   = (float*)d_out;

  proj3<<<dim3(32, 4, 4), 256, 0, stream>>>(key, value, query, Wk, Wq, Wva, Wal,
                                            kproj, vproj, qpF, WalF, vsum, out);
  kernelC<<<dim3(16, 8, 2), 512, 0, stream>>>(qpF, kproj, vproj, WalF, vsum);
  gemm_out<<<dim3(32, 4, 2), 256, 0, stream>>>(vsum, Wvo, out);
}